// Round 2
// 3382.702 us; speedup vs baseline: 2.1050x; 2.1050x over previous
//
#include <hip/hip_runtime.h>

// SNN: two recurrent LIF layers + linear readout.
// B=256, T=100, F=256, H=1024, O=8. All fp32.
//
// Round 3: fused per-batch scan (round 2) with BIT-EXACT rec summation.
//   Round-2 failure: active-row sum used word-grouped order + pairwise tree
//   -> different rounding -> spike flips -> absmax 3.96 > 2.23.
//   Fix: active list built in ASCENDING k order (two-level ballot prefix sum),
//   summed sequentially -> bit-identical to the round-0 passing kernel
//   (skipping zero rows is exact: fmaf(0,R,acc)==acc, fmaf(1,R,acc)==acc+R).

#define SNN_B 256
#define SNN_T 100
#define SNN_F 256
#define SNN_H 1024
#define SNN_O 8

#define ALPHA 0.9048374180359595f  // exp(-0.1)
#define BETA  0.8187307530779818f  // exp(-0.2)

// ---------------------------------------------------------------------------
// Generic fp32 GEMM: C[M,N] = A[M,K] @ B[K,N], all row-major. (unchanged)
// ---------------------------------------------------------------------------
__global__ __launch_bounds__(256) void gemm_f32(
    const float* __restrict__ A, const float* __restrict__ Bm,
    float* __restrict__ C, int M, int N, int K)
{
    __shared__ float As[16][68];   // [k][m], padded
    __shared__ float Bs[16][64];   // [k][n]

    const int tid = threadIdx.x;
    const int m0 = blockIdx.y * 64;
    const int n0 = blockIdx.x * 64;
    const int tm = tid >> 4;          // 0..15
    const int tn = tid & 15;          // 0..15

    const int lrowA = tid >> 2;       // 0..63
    const int lkA   = (tid & 3) * 4;  // 0,4,8,12
    const int lkB   = tid >> 4;       // 0..15
    const int lnB   = (tid & 15) * 4; // 0..60

    float acc[4][4] = {};

    for (int k0 = 0; k0 < K; k0 += 16) {
        float4 a = *(const float4*)&A[(size_t)(m0 + lrowA) * K + k0 + lkA];
        As[lkA + 0][lrowA] = a.x;
        As[lkA + 1][lrowA] = a.y;
        As[lkA + 2][lrowA] = a.z;
        As[lkA + 3][lrowA] = a.w;
        *(float4*)&Bs[lkB][lnB] =
            *(const float4*)&Bm[(size_t)(k0 + lkB) * N + n0 + lnB];
        __syncthreads();
        #pragma unroll
        for (int k = 0; k < 16; ++k) {
            float4 av = *(const float4*)&As[k][tm * 4];
            float4 bv = *(const float4*)&Bs[k][tn * 4];
            float am[4] = {av.x, av.y, av.z, av.w};
            float bn[4] = {bv.x, bv.y, bv.z, bv.w};
            #pragma unroll
            for (int i = 0; i < 4; ++i)
                #pragma unroll
                for (int j = 0; j < 4; ++j)
                    acc[i][j] = fmaf(am[i], bn[j], acc[i][j]);
        }
        __syncthreads();
    }

    #pragma unroll
    for (int i = 0; i < 4; ++i) {
        float4 o = make_float4(acc[i][0], acc[i][1], acc[i][2], acc[i][3]);
        *(float4*)&C[(size_t)(m0 + tm * 4 + i) * N + n0 + tn * 4] = o;
    }
}

// ---------------------------------------------------------------------------
// Fused LIF layer scan. One block per batch; 256 threads, 4 columns each.
// State (cur, pot) lives in registers for all 100 steps. Each step:
//   rec = sum over active-k list (spikes t-1) of R[k, j], ASCENDING k,
//         sequential adds -> bit-identical to a dense ascending-k FMA chain.
//   spk = (pot - 1 > 0); cur = a*cur + h + rec; pot = (b*pot + cur)*(1-spk)
// Active list rebuilt each step via ballots + two-level exclusive prefix sum
// (deterministic, ascending k).
// ---------------------------------------------------------------------------
__global__ __launch_bounds__(256) void lif_scan(
    const float* __restrict__ hbuf,  // [B,T,H]
    const float* __restrict__ R,     // [H,H]
    float* __restrict__ s_out,       // [B,T,H]
    float* __restrict__ v_out)       // [B,T,H]
{
    __shared__ __align__(16) int slist[SNN_H];     // active k indices (ascending)
    __shared__ int wtot[4];                        // per-wave spike counts
    __shared__ int sn;                             // total active count

    const int tid = threadIdx.x;
    const int b = blockIdx.x;
    const int c4 = tid << 2;                       // first of this thread's 4 cols
    const int wv = tid >> 6;                       // wave 0..3
    const int lane = tid & 63;
    const float* __restrict__ Rc = R + c4;

    float4 cur = make_float4(0.f, 0.f, 0.f, 0.f);
    float4 pot = make_float4(0.f, 0.f, 0.f, 0.f);

    if (tid == 0) sn = 0;
    __syncthreads();

    const float* hrow = hbuf + (size_t)b * SNN_T * SNN_H + c4;
    float*       srow = s_out + (size_t)b * SNN_T * SNN_H + c4;
    float*       vrow = v_out + (size_t)b * SNN_T * SNN_H + c4;

    for (int t = 0; t < SNN_T; ++t) {
        float4 hv = *(const float4*)hrow;          // issue early, hide under rec
        hrow += SNN_H;

        // ---- rec from active rows of R (spikes of step t-1), ascending k ----
        // Sequential adds per accumulator preserve the exact FP order of the
        // dense ascending-k FMA chain (zero rows are exact no-ops).
        const int n = sn;
        float a0 = 0.f, a1 = 0.f, a2 = 0.f, a3 = 0.f;
        int i = 0;
        for (; i + 4 <= n; i += 4) {               // depth-4 load pipeline
            const int4 ks = *(const int4*)&slist[i];
            const float4 r0 = *(const float4*)(Rc + ((size_t)ks.x << 10));
            const float4 r1 = *(const float4*)(Rc + ((size_t)ks.y << 10));
            const float4 r2 = *(const float4*)(Rc + ((size_t)ks.z << 10));
            const float4 r3 = *(const float4*)(Rc + ((size_t)ks.w << 10));
            a0 += r0.x; a0 += r1.x; a0 += r2.x; a0 += r3.x;
            a1 += r0.y; a1 += r1.y; a1 += r2.y; a1 += r3.y;
            a2 += r0.z; a2 += r1.z; a2 += r2.z; a2 += r3.z;
            a3 += r0.w; a3 += r1.w; a3 += r2.w; a3 += r3.w;
        }
        for (; i < n; ++i) {
            const float4 r0 = *(const float4*)(Rc + ((size_t)slist[i] << 10));
            a0 += r0.x; a1 += r0.y; a2 += r0.z; a3 += r0.w;
        }

        // ---- spikes from pot(t-1), then state update (same forms as round 0) ----
        const bool p0 = (pot.x - 1.0f) > 0.0f;
        const bool p1 = (pot.y - 1.0f) > 0.0f;
        const bool p2 = (pot.z - 1.0f) > 0.0f;
        const bool p3 = (pot.w - 1.0f) > 0.0f;
        const float s0 = p0 ? 1.0f : 0.0f;
        const float s1v = p1 ? 1.0f : 0.0f;
        const float s2v = p2 ? 1.0f : 0.0f;
        const float s3 = p3 ? 1.0f : 0.0f;

        cur.x = fmaf(ALPHA, cur.x, hv.x) + a0;
        cur.y = fmaf(ALPHA, cur.y, hv.y) + a1;
        cur.z = fmaf(ALPHA, cur.z, hv.z) + a2;
        cur.w = fmaf(ALPHA, cur.w, hv.w) + a3;
        pot.x = fmaf(BETA, pot.x, cur.x) * (1.0f - s0);
        pot.y = fmaf(BETA, pot.y, cur.y) * (1.0f - s1v);
        pot.z = fmaf(BETA, pot.z, cur.z) * (1.0f - s2v);
        pot.w = fmaf(BETA, pot.w, cur.w) * (1.0f - s3);

        *(float4*)srow = make_float4(s0, s1v, s2v, s3);
        *(float4*)vrow = pot;
        srow += SNN_H; vrow += SNN_H;

        // ---- build next step's active list, ASCENDING k ----
        // k = 4*tid + jj. Exclusive offset = (spikes in waves < wv)
        //   + (spikes in lower lanes of this wave) + (lower jj of this thread).
        const unsigned long long m0 = __ballot(p0);
        const unsigned long long m1 = __ballot(p1);
        const unsigned long long m2 = __ballot(p2);
        const unsigned long long m3 = __ballot(p3);
        const unsigned long long lt = (1ull << lane) - 1ull;
        const int lpre = __popcll(m0 & lt) + __popcll(m1 & lt)
                       + __popcll(m2 & lt) + __popcll(m3 & lt);
        const int wt = __popcll(m0) + __popcll(m1) + __popcll(m2) + __popcll(m3);
        if (lane == 0) wtot[wv] = wt;
        __syncthreads();   // wtot ready AND all threads done reading slist
        int off = lpre;
        #pragma unroll
        for (int q = 0; q < 3; ++q)
            if (q < wv) off += wtot[q];
        if (p0) slist[off++] = c4 + 0;
        if (p1) slist[off++] = c4 + 1;
        if (p2) slist[off++] = c4 + 2;
        if (p3) slist[off++] = c4 + 3;
        if (tid == 0) sn = wtot[0] + wtot[1] + wtot[2] + wtot[3];
        __syncthreads();   // slist/sn ready for step t+1
    }
}

// ---------------------------------------------------------------------------
// Readout GEMM: h3[row, o] = sum_k s2[row, k] * Wout[k, o]. (unchanged)
// ---------------------------------------------------------------------------
__global__ __launch_bounds__(256) void readout_gemm(
    const float* __restrict__ s2in, const float* __restrict__ Wout,
    float* __restrict__ h3)
{
    const int gid = blockIdx.x * 256 + threadIdx.x;
    const int row = gid >> 3;
    const int o = gid & 7;
    const float* srow = s2in + (size_t)row * SNN_H;
    float acc = 0.f;
    for (int k = 0; k < SNN_H; k += 4) {
        float4 s = *(const float4*)&srow[k];
        acc = fmaf(s.x, Wout[(k + 0) * SNN_O + o], acc);
        acc = fmaf(s.y, Wout[(k + 1) * SNN_O + o], acc);
        acc = fmaf(s.z, Wout[(k + 2) * SNN_O + o], acc);
        acc = fmaf(s.w, Wout[(k + 3) * SNN_O + o], acc);
    }
    h3[(size_t)row * SNN_O + o] = acc;
}

// ---------------------------------------------------------------------------
// Readout linear scan. (unchanged)
// ---------------------------------------------------------------------------
__global__ __launch_bounds__(256) void readout_scan(
    const float* __restrict__ h3, float* __restrict__ out)
{
    const int gid = blockIdx.x * 256 + threadIdx.x;  // 2048 = B*O
    const int b = gid >> 3;
    const int o = gid & 7;
    float c = 0.f, p = 0.f;
    out[((size_t)b * (SNN_T + 1) + 0) * SNN_O + o] = 0.f;
    for (int t = 0; t < SNN_T; ++t) {
        c = fmaf(ALPHA, c, h3[((size_t)b * SNN_T + t) * SNN_O + o]);
        p = fmaf(BETA, p, c);
        out[((size_t)b * (SNN_T + 1) + t + 1) * SNN_O + o] = p;
    }
}

// ---------------------------------------------------------------------------
extern "C" void kernel_launch(void* const* d_in, const int* in_sizes, int n_in,
                              void* d_out, int out_size, void* d_ws, size_t ws_size,
                              hipStream_t stream)
{
    const float* X    = (const float*)d_in[0];  // [B,T,F]
    const float* W0   = (const float*)d_in[1];  // [F,H]
    const float* W1   = (const float*)d_in[2];  // [H,H]
    const float* R0   = (const float*)d_in[3];  // [H,H]
    const float* R1   = (const float*)d_in[4];  // [H,H]
    const float* Wout = (const float*)d_in[5];  // [H,O]

    const size_t BT_H = (size_t)SNN_B * SNN_T * SNN_H;  // 26,214,400
    float* out = (float*)d_out;                          // [B,T+1,O]
    float* s1  = out + (size_t)SNN_B * (SNN_T + 1) * SNN_O;
    float* s2  = s1 + BT_H;
    float* v1  = s2 + BT_H;
    float* v2  = v1 + BT_H;

    float* ws   = (float*)d_ws;
    float* hbuf = ws;                       // [B*T*H] (h1, then reused for h2)
    float* h3   = hbuf + BT_H;              // [B*T*O]

    const int M = SNN_B * SNN_T;  // 25600

    // h1 = X @ W0
    gemm_f32<<<dim3(SNN_H / 64, M / 64), 256, 0, stream>>>(X, W0, hbuf, M, SNN_H, SNN_F);

    // layer-1 fused scan (100 steps in one launch)
    lif_scan<<<SNN_B, 256, 0, stream>>>(hbuf, R0, s1, v1);

    // h2 = s1 @ W1 (reuse hbuf)
    gemm_f32<<<dim3(SNN_H / 64, M / 64), 256, 0, stream>>>(s1, W1, hbuf, M, SNN_H, SNN_H);

    // layer-2 fused scan
    lif_scan<<<SNN_B, 256, 0, stream>>>(hbuf, R1, s2, v2);

    // readout
    readout_gemm<<<(M * SNN_O) / 256, 256, 0, stream>>>(s2, Wout, h3);
    readout_scan<<<(SNN_B * SNN_O) / 256, 256, 0, stream>>>(h3, out);
}

// Round 3
// 3171.701 us; speedup vs baseline: 2.2450x; 1.0665x over previous
//
#include <hip/hip_runtime.h>

// SNN: two recurrent LIF layers + linear readout.
// B=256, T=100, F=256, H=1024, O=8. All fp32.
//
// Round 4: lif_scan re-partitioned for latency hiding.
//   Round-3 counters: Occupancy 11.7% (4 waves/CU), VALUBusy 20%, HBM 4-7%
//   -> latency-bound L2 row-gather. Fix:
//   (a) 1024 threads/block, 1 column/thread -> 16 waves/CU.
//   (b) gather double-buffered in registers with ROLE ALTERNATION (no c=d
//       moves -> no vmcnt(0) drain per iteration).
//   Summation order unchanged (ascending k, sequential adds per column)
//   -> bit-identical to the round-0/round-3 passing kernels.

#define SNN_B 256
#define SNN_T 100
#define SNN_F 256
#define SNN_H 1024
#define SNN_O 8

#define ALPHA 0.9048374180359595f  // exp(-0.1)
#define BETA  0.8187307530779818f  // exp(-0.2)

// ---------------------------------------------------------------------------
// Generic fp32 GEMM: C[M,N] = A[M,K] @ B[K,N], all row-major. (unchanged)
// ---------------------------------------------------------------------------
__global__ __launch_bounds__(256) void gemm_f32(
    const float* __restrict__ A, const float* __restrict__ Bm,
    float* __restrict__ C, int M, int N, int K)
{
    __shared__ float As[16][68];   // [k][m], padded
    __shared__ float Bs[16][64];   // [k][n]

    const int tid = threadIdx.x;
    const int m0 = blockIdx.y * 64;
    const int n0 = blockIdx.x * 64;
    const int tm = tid >> 4;          // 0..15
    const int tn = tid & 15;          // 0..15

    const int lrowA = tid >> 2;       // 0..63
    const int lkA   = (tid & 3) * 4;  // 0,4,8,12
    const int lkB   = tid >> 4;       // 0..15
    const int lnB   = (tid & 15) * 4; // 0..60

    float acc[4][4] = {};

    for (int k0 = 0; k0 < K; k0 += 16) {
        float4 a = *(const float4*)&A[(size_t)(m0 + lrowA) * K + k0 + lkA];
        As[lkA + 0][lrowA] = a.x;
        As[lkA + 1][lrowA] = a.y;
        As[lkA + 2][lrowA] = a.z;
        As[lkA + 3][lrowA] = a.w;
        *(float4*)&Bs[lkB][lnB] =
            *(const float4*)&Bm[(size_t)(k0 + lkB) * N + n0 + lnB];
        __syncthreads();
        #pragma unroll
        for (int k = 0; k < 16; ++k) {
            float4 av = *(const float4*)&As[k][tm * 4];
            float4 bv = *(const float4*)&Bs[k][tn * 4];
            float am[4] = {av.x, av.y, av.z, av.w};
            float bn[4] = {bv.x, bv.y, bv.z, bv.w};
            #pragma unroll
            for (int i = 0; i < 4; ++i)
                #pragma unroll
                for (int j = 0; j < 4; ++j)
                    acc[i][j] = fmaf(am[i], bn[j], acc[i][j]);
        }
        __syncthreads();
    }

    #pragma unroll
    for (int i = 0; i < 4; ++i) {
        float4 o = make_float4(acc[i][0], acc[i][1], acc[i][2], acc[i][3]);
        *(float4*)&C[(size_t)(m0 + tm * 4 + i) * N + n0 + tn * 4] = o;
    }
}

// ---------------------------------------------------------------------------
// Fused LIF layer scan. One block per batch; 1024 threads, ONE column each
// (16 waves/CU for latency hiding). State (cur, pot) in registers.
// Per step:
//   rec = sum over active-k list (spikes t-1) of R[k, j], ascending k,
//         sequential adds -> bit-identical to dense ascending-k chain.
//   spk = (pot - 1 > 0); cur = a*cur + h + rec; pot = (b*pot + cur)*(1-spk)
// Active list rebuilt via ballots + two-level exclusive prefix (ascending k).
// Gather uses two 8-row register buffers with role alternation so each SUM
// waits only on loads issued one full stage earlier.
// ---------------------------------------------------------------------------

#define LIF_LOAD(Xa, Xb, Xc, Xd, Xe, Xf, Xg, Xh, cidx)                        \
    {                                                                         \
        const int4 ka_ = *(const int4*)&slist[(cidx) << 3];                   \
        const int4 kb_ = *(const int4*)&slist[((cidx) << 3) + 4];             \
        Xa = Rc[(size_t)ka_.x << 10];                                         \
        Xb = Rc[(size_t)ka_.y << 10];                                         \
        Xc = Rc[(size_t)ka_.z << 10];                                         \
        Xd = Rc[(size_t)ka_.w << 10];                                         \
        Xe = Rc[(size_t)kb_.x << 10];                                         \
        Xf = Rc[(size_t)kb_.y << 10];                                         \
        Xg = Rc[(size_t)kb_.z << 10];                                         \
        Xh = Rc[(size_t)kb_.w << 10];                                         \
    }

#define LIF_SUM(Xa, Xb, Xc, Xd, Xe, Xf, Xg, Xh)                               \
    {                                                                         \
        a0 += Xa; a0 += Xb; a0 += Xc; a0 += Xd;                               \
        a0 += Xe; a0 += Xf; a0 += Xg; a0 += Xh;                               \
    }

__global__ __launch_bounds__(1024) void lif_scan(
    const float* __restrict__ hbuf,  // [B,T,H]
    const float* __restrict__ R,     // [H,H]
    float* __restrict__ s_out,       // [B,T,H]
    float* __restrict__ v_out)       // [B,T,H]
{
    __shared__ __align__(16) int slist[SNN_H];     // active k indices (ascending)
    __shared__ int wtot[16];                       // per-wave spike counts
    __shared__ int sn;                             // total active count

    const int tid = threadIdx.x;                   // == column j
    const int b = blockIdx.x;
    const int wv = tid >> 6;                       // wave 0..15
    const int lane = tid & 63;
    const float* __restrict__ Rc = R + tid;

    float cur = 0.f, pot = 0.f;

    if (tid == 0) sn = 0;
    __syncthreads();

    const float* hrow = hbuf + (size_t)b * SNN_T * SNN_H + tid;
    float*       srow = s_out + (size_t)b * SNN_T * SNN_H + tid;
    float*       vrow = v_out + (size_t)b * SNN_T * SNN_H + tid;

    for (int t = 0; t < SNN_T; ++t) {
        const float hv = *hrow;                    // issue early, hide under rec
        hrow += SNN_H;

        // ---- rec from active rows of R (spikes t-1), ascending k ----
        const int n = sn;
        float a0 = 0.f;
        int i = 0;
        const int nc = n >> 3;                     // full 8-chunks
        if (nc > 0) {
            float A0, A1, A2, A3, A4, A5, A6, A7;
            float B0, B1, B2, B3, B4, B5, B6, B7;
            LIF_LOAD(A0, A1, A2, A3, A4, A5, A6, A7, 0);
            int c = 1;
            for (; c + 1 < nc; c += 2) {
                LIF_LOAD(B0, B1, B2, B3, B4, B5, B6, B7, c);
                LIF_SUM(A0, A1, A2, A3, A4, A5, A6, A7);       // chunk c-1
                LIF_LOAD(A0, A1, A2, A3, A4, A5, A6, A7, c + 1);
                LIF_SUM(B0, B1, B2, B3, B4, B5, B6, B7);       // chunk c
            }
            if (c < nc) {
                LIF_LOAD(B0, B1, B2, B3, B4, B5, B6, B7, c);
                LIF_SUM(A0, A1, A2, A3, A4, A5, A6, A7);       // chunk c-1
                LIF_SUM(B0, B1, B2, B3, B4, B5, B6, B7);       // chunk c
            } else {
                LIF_SUM(A0, A1, A2, A3, A4, A5, A6, A7);       // last chunk
            }
            i = nc << 3;
        }
        for (; i < n; ++i)
            a0 += Rc[(size_t)slist[i] << 10];

        // ---- spike from pot(t-1), state update (same forms as round 0) ----
        const bool p = (pot - 1.0f) > 0.0f;
        const float s = p ? 1.0f : 0.0f;
        cur = fmaf(ALPHA, cur, hv) + a0;
        pot = fmaf(BETA, pot, cur) * (1.0f - s);

        *srow = s;
        *vrow = pot;
        srow += SNN_H; vrow += SNN_H;

        // ---- build next step's active list, ASCENDING k ----
        // col j = 64*wv + lane; offset = spikes in waves < wv
        //   + spikes in lower lanes of this wave.
        const unsigned long long m = __ballot(p);
        const unsigned long long lt = (1ull << lane) - 1ull;
        const int lpre = __popcll(m & lt);
        if (lane == 0) wtot[wv] = __popcll(m);
        __syncthreads();   // wtot ready AND all threads done reading slist
        int off = lpre;
        #pragma unroll
        for (int q = 0; q < 15; ++q)
            if (q < wv) off += wtot[q];
        if (p) slist[off] = tid;
        if (tid == 0) {
            int stot = 0;
            #pragma unroll
            for (int q = 0; q < 16; ++q) stot += wtot[q];
            sn = stot;
        }
        __syncthreads();   // slist/sn ready for step t+1
    }
}

// ---------------------------------------------------------------------------
// Readout GEMM: h3[row, o] = sum_k s2[row, k] * Wout[k, o]. (unchanged)
// ---------------------------------------------------------------------------
__global__ __launch_bounds__(256) void readout_gemm(
    const float* __restrict__ s2in, const float* __restrict__ Wout,
    float* __restrict__ h3)
{
    const int gid = blockIdx.x * 256 + threadIdx.x;
    const int row = gid >> 3;
    const int o = gid & 7;
    const float* srow = s2in + (size_t)row * SNN_H;
    float acc = 0.f;
    for (int k = 0; k < SNN_H; k += 4) {
        float4 s = *(const float4*)&srow[k];
        acc = fmaf(s.x, Wout[(k + 0) * SNN_O + o], acc);
        acc = fmaf(s.y, Wout[(k + 1) * SNN_O + o], acc);
        acc = fmaf(s.z, Wout[(k + 2) * SNN_O + o], acc);
        acc = fmaf(s.w, Wout[(k + 3) * SNN_O + o], acc);
    }
    h3[(size_t)row * SNN_O + o] = acc;
}

// ---------------------------------------------------------------------------
// Readout linear scan. (unchanged)
// ---------------------------------------------------------------------------
__global__ __launch_bounds__(256) void readout_scan(
    const float* __restrict__ h3, float* __restrict__ out)
{
    const int gid = blockIdx.x * 256 + threadIdx.x;  // 2048 = B*O
    const int b = gid >> 3;
    const int o = gid & 7;
    float c = 0.f, p = 0.f;
    out[((size_t)b * (SNN_T + 1) + 0) * SNN_O + o] = 0.f;
    for (int t = 0; t < SNN_T; ++t) {
        c = fmaf(ALPHA, c, h3[((size_t)b * SNN_T + t) * SNN_O + o]);
        p = fmaf(BETA, p, c);
        out[((size_t)b * (SNN_T + 1) + t + 1) * SNN_O + o] = p;
    }
}

// ---------------------------------------------------------------------------
extern "C" void kernel_launch(void* const* d_in, const int* in_sizes, int n_in,
                              void* d_out, int out_size, void* d_ws, size_t ws_size,
                              hipStream_t stream)
{
    const float* X    = (const float*)d_in[0];  // [B,T,F]
    const float* W0   = (const float*)d_in[1];  // [F,H]
    const float* W1   = (const float*)d_in[2];  // [H,H]
    const float* R0   = (const float*)d_in[3];  // [H,H]
    const float* R1   = (const float*)d_in[4];  // [H,H]
    const float* Wout = (const float*)d_in[5];  // [H,O]

    const size_t BT_H = (size_t)SNN_B * SNN_T * SNN_H;  // 26,214,400
    float* out = (float*)d_out;                          // [B,T+1,O]
    float* s1  = out + (size_t)SNN_B * (SNN_T + 1) * SNN_O;
    float* s2  = s1 + BT_H;
    float* v1  = s2 + BT_H;
    float* v2  = v1 + BT_H;

    float* ws   = (float*)d_ws;
    float* hbuf = ws;                       // [B*T*H] (h1, then reused for h2)
    float* h3   = hbuf + BT_H;              // [B*T*O]

    const int M = SNN_B * SNN_T;  // 25600

    // h1 = X @ W0
    gemm_f32<<<dim3(SNN_H / 64, M / 64), 256, 0, stream>>>(X, W0, hbuf, M, SNN_H, SNN_F);

    // layer-1 fused scan (100 steps in one launch)
    lif_scan<<<SNN_B, 1024, 0, stream>>>(hbuf, R0, s1, v1);

    // h2 = s1 @ W1 (reuse hbuf)
    gemm_f32<<<dim3(SNN_H / 64, M / 64), 256, 0, stream>>>(s1, W1, hbuf, M, SNN_H, SNN_H);

    // layer-2 fused scan
    lif_scan<<<SNN_B, 1024, 0, stream>>>(hbuf, R1, s2, v2);

    // readout
    readout_gemm<<<(M * SNN_O) / 256, 256, 0, stream>>>(s2, Wout, h3);
    readout_scan<<<(SNN_B * SNN_O) / 256, 256, 0, stream>>>(h3, out);
}

// Round 4
// 3107.890 us; speedup vs baseline: 2.2911x; 1.0205x over previous
//
#include <hip/hip_runtime.h>

// SNN: two recurrent LIF layers + linear readout.
// B=256, T=100, F=256, H=1024, O=8. All fp32.
//
// Round 5:
//   - gemm_f32 rewritten: 128x128 tile, BK=8, 8x8 micro-tile, double-buffered
//     LDS (global loads issued during compute). Still one accumulator per
//     output, strictly ascending k -> bit-identical results.
//   - lif_scan: 32-bit uniform-base addressing for the R row gather
//     (R[(k<<10)|tid], fits 4MB) -> saddr global_load, ~2 fewer VALU/row.
//     Scan is at the L2-BW roofline (~400 active rows x 4KB x 256 blocks
//     per step ~= 12 us/step); this relieves the 77% VALU pressure.
//   - Summation orders everywhere unchanged (chaos-sensitive recurrence).

#define SNN_B 256
#define SNN_T 100
#define SNN_F 256
#define SNN_H 1024
#define SNN_O 8

#define ALPHA 0.9048374180359595f  // exp(-0.1)
#define BETA  0.8187307530779818f  // exp(-0.2)

// ---------------------------------------------------------------------------
// fp32 GEMM: C[M,N] = A[M,K] @ B[K,N], row-major. 128x128 tile, BK=8,
// 256 threads, 8x8 micro-tile, double-buffered LDS.
// Per-output accumulation is a single fmaf chain over ascending k
// -> bit-identical to the previous 64x64 kernel.
// Requires M%128==0, N%128==0, K%8==0.
// ---------------------------------------------------------------------------
__global__ __launch_bounds__(256) void gemm_f32(
    const float* __restrict__ A, const float* __restrict__ Bm,
    float* __restrict__ C, int M, int N, int K)
{
    __shared__ float As[2][8][132];   // [buf][k][m], padded
    __shared__ float Bs[2][8][132];   // [buf][k][n], padded

    const int tid = threadIdx.x;
    const int m0 = blockIdx.y * 128;
    const int n0 = blockIdx.x * 128;
    const int ty = tid >> 4;           // 0..15 -> rows ty*8..+7
    const int tx = tid & 15;           // 0..15 -> cols tx*8..+7

    // staging: A tile 128x8 = 256 float4 (along k); B tile 8x128 = 256 float4
    const int arow = tid >> 1;          // 0..127
    const int akq  = (tid & 1) * 4;     // 0 or 4
    const int bkr  = tid >> 5;          // 0..7
    const int bnq  = (tid & 31) * 4;    // 0..124

    const float* Aptr = A + (size_t)(m0 + arow) * K + akq;
    const float* Bptr = Bm + (size_t)bkr * N + n0 + bnq;

    // prologue: stage k-tile 0 into buffer 0
    float4 ar = *(const float4*)Aptr;
    float4 br = *(const float4*)Bptr;
    As[0][akq + 0][arow] = ar.x;
    As[0][akq + 1][arow] = ar.y;
    As[0][akq + 2][arow] = ar.z;
    As[0][akq + 3][arow] = ar.w;
    *(float4*)&Bs[0][bkr][bnq] = br;
    __syncthreads();

    float acc[8][8] = {};
    const int NK = K >> 3;

    for (int kt = 0; kt < NK; ++kt) {
        const int cur = kt & 1;
        if (kt + 1 < NK) {               // issue next tile's loads early
            ar = *(const float4*)(Aptr + (kt + 1) * 8);
            br = *(const float4*)(Bptr + (size_t)(kt + 1) * 8 * N);
        }
        #pragma unroll
        for (int k = 0; k < 8; ++k) {
            const float4 a0 = *(const float4*)&As[cur][k][ty * 8];
            const float4 a1 = *(const float4*)&As[cur][k][ty * 8 + 4];
            const float4 b0 = *(const float4*)&Bs[cur][k][tx * 8];
            const float4 b1 = *(const float4*)&Bs[cur][k][tx * 8 + 4];
            const float am[8] = {a0.x, a0.y, a0.z, a0.w, a1.x, a1.y, a1.z, a1.w};
            const float bn[8] = {b0.x, b0.y, b0.z, b0.w, b1.x, b1.y, b1.z, b1.w};
            #pragma unroll
            for (int i = 0; i < 8; ++i)
                #pragma unroll
                for (int j = 0; j < 8; ++j)
                    acc[i][j] = fmaf(am[i], bn[j], acc[i][j]);
        }
        if (kt + 1 < NK) {
            const int nxt = cur ^ 1;
            __syncthreads();             // prior reads of buffer nxt complete
            As[nxt][akq + 0][arow] = ar.x;
            As[nxt][akq + 1][arow] = ar.y;
            As[nxt][akq + 2][arow] = ar.z;
            As[nxt][akq + 3][arow] = ar.w;
            *(float4*)&Bs[nxt][bkr][bnq] = br;
            __syncthreads();             // writes visible before next compute
        }
    }

    #pragma unroll
    for (int i = 0; i < 8; ++i) {
        float* crow = C + (size_t)(m0 + ty * 8 + i) * N + n0 + tx * 8;
        *(float4*)crow = make_float4(acc[i][0], acc[i][1], acc[i][2], acc[i][3]);
        *(float4*)(crow + 4) = make_float4(acc[i][4], acc[i][5], acc[i][6], acc[i][7]);
    }
}

// ---------------------------------------------------------------------------
// Fused LIF layer scan. One block per batch; 1024 threads, ONE column each.
// rec gathered over active rows (ascending k, sequential adds -> bit-exact).
// R indexed with 32-bit offsets from the uniform base (saddr form).
// ---------------------------------------------------------------------------

#define LIF_LOAD(Xa, Xb, Xc, Xd, Xe, Xf, Xg, Xh, cidx)                        \
    {                                                                         \
        const int4 ka_ = *(const int4*)&slist[(cidx) << 3];                   \
        const int4 kb_ = *(const int4*)&slist[(((cidx) << 3) + 4)];           \
        Xa = R[((unsigned)ka_.x << 10) | ctid];                               \
        Xb = R[((unsigned)ka_.y << 10) | ctid];                               \
        Xc = R[((unsigned)ka_.z << 10) | ctid];                               \
        Xd = R[((unsigned)ka_.w << 10) | ctid];                               \
        Xe = R[((unsigned)kb_.x << 10) | ctid];                               \
        Xf = R[((unsigned)kb_.y << 10) | ctid];                               \
        Xg = R[((unsigned)kb_.z << 10) | ctid];                               \
        Xh = R[((unsigned)kb_.w << 10) | ctid];                               \
    }

#define LIF_SUM(Xa, Xb, Xc, Xd, Xe, Xf, Xg, Xh)                               \
    {                                                                         \
        a0 += Xa; a0 += Xb; a0 += Xc; a0 += Xd;                               \
        a0 += Xe; a0 += Xf; a0 += Xg; a0 += Xh;                               \
    }

__global__ __launch_bounds__(1024) void lif_scan(
    const float* __restrict__ hbuf,  // [B,T,H]
    const float* __restrict__ R,     // [H,H]
    float* __restrict__ s_out,       // [B,T,H]
    float* __restrict__ v_out)       // [B,T,H]
{
    __shared__ __align__(16) int slist[SNN_H];     // active k indices (ascending)
    __shared__ int wtot[16];                       // per-wave spike counts
    __shared__ int sn;                             // total active count

    const int tid = threadIdx.x;                   // == column j
    const unsigned ctid = (unsigned)tid;
    const int b = blockIdx.x;
    const int wv = tid >> 6;                       // wave 0..15
    const int lane = tid & 63;

    float cur = 0.f, pot = 0.f;

    if (tid == 0) sn = 0;
    __syncthreads();

    const float* hrow = hbuf + (size_t)b * SNN_T * SNN_H + tid;
    float*       srow = s_out + (size_t)b * SNN_T * SNN_H + tid;
    float*       vrow = v_out + (size_t)b * SNN_T * SNN_H + tid;

    for (int t = 0; t < SNN_T; ++t) {
        const float hv = *hrow;                    // issue early, hide under rec
        hrow += SNN_H;

        // ---- rec from active rows of R (spikes t-1), ascending k ----
        const int n = sn;
        float a0 = 0.f;
        int i = 0;
        const int nc = n >> 3;                     // full 8-chunks
        if (nc > 0) {
            float A0, A1, A2, A3, A4, A5, A6, A7;
            float B0, B1, B2, B3, B4, B5, B6, B7;
            LIF_LOAD(A0, A1, A2, A3, A4, A5, A6, A7, 0);
            int c = 1;
            for (; c + 1 < nc; c += 2) {
                LIF_LOAD(B0, B1, B2, B3, B4, B5, B6, B7, c);
                LIF_SUM(A0, A1, A2, A3, A4, A5, A6, A7);       // chunk c-1
                LIF_LOAD(A0, A1, A2, A3, A4, A5, A6, A7, c + 1);
                LIF_SUM(B0, B1, B2, B3, B4, B5, B6, B7);       // chunk c
            }
            if (c < nc) {
                LIF_LOAD(B0, B1, B2, B3, B4, B5, B6, B7, c);
                LIF_SUM(A0, A1, A2, A3, A4, A5, A6, A7);       // chunk c-1
                LIF_SUM(B0, B1, B2, B3, B4, B5, B6, B7);       // chunk c
            } else {
                LIF_SUM(A0, A1, A2, A3, A4, A5, A6, A7);       // last chunk
            }
            i = nc << 3;
        }
        for (; i < n; ++i)
            a0 += R[((unsigned)slist[i] << 10) | ctid];

        // ---- spike from pot(t-1), state update (same forms as round 0) ----
        const bool p = (pot - 1.0f) > 0.0f;
        const float s = p ? 1.0f : 0.0f;
        cur = fmaf(ALPHA, cur, hv) + a0;
        pot = fmaf(BETA, pot, cur) * (1.0f - s);

        *srow = s;
        *vrow = pot;
        srow += SNN_H; vrow += SNN_H;

        // ---- build next step's active list, ASCENDING k ----
        const unsigned long long m = __ballot(p);
        const unsigned long long lt = (1ull << lane) - 1ull;
        const int lpre = __popcll(m & lt);
        if (lane == 0) wtot[wv] = __popcll(m);
        __syncthreads();   // wtot ready AND all threads done reading slist
        int off = lpre;
        #pragma unroll
        for (int q = 0; q < 15; ++q)
            if (q < wv) off += wtot[q];
        if (p) slist[off] = tid;
        if (tid == 0) {
            int stot = 0;
            #pragma unroll
            for (int q = 0; q < 16; ++q) stot += wtot[q];
            sn = stot;
        }
        __syncthreads();   // slist/sn ready for step t+1
    }
}

// ---------------------------------------------------------------------------
// Readout GEMM: h3[row, o] = sum_k s2[row, k] * Wout[k, o]. (unchanged)
// ---------------------------------------------------------------------------
__global__ __launch_bounds__(256) void readout_gemm(
    const float* __restrict__ s2in, const float* __restrict__ Wout,
    float* __restrict__ h3)
{
    const int gid = blockIdx.x * 256 + threadIdx.x;
    const int row = gid >> 3;
    const int o = gid & 7;
    const float* srow = s2in + (size_t)row * SNN_H;
    float acc = 0.f;
    for (int k = 0; k < SNN_H; k += 4) {
        float4 s = *(const float4*)&srow[k];
        acc = fmaf(s.x, Wout[(k + 0) * SNN_O + o], acc);
        acc = fmaf(s.y, Wout[(k + 1) * SNN_O + o], acc);
        acc = fmaf(s.z, Wout[(k + 2) * SNN_O + o], acc);
        acc = fmaf(s.w, Wout[(k + 3) * SNN_O + o], acc);
    }
    h3[(size_t)row * SNN_O + o] = acc;
}

// ---------------------------------------------------------------------------
// Readout linear scan. (unchanged)
// ---------------------------------------------------------------------------
__global__ __launch_bounds__(256) void readout_scan(
    const float* __restrict__ h3, float* __restrict__ out)
{
    const int gid = blockIdx.x * 256 + threadIdx.x;  // 2048 = B*O
    const int b = gid >> 3;
    const int o = gid & 7;
    float c = 0.f, p = 0.f;
    out[((size_t)b * (SNN_T + 1) + 0) * SNN_O + o] = 0.f;
    for (int t = 0; t < SNN_T; ++t) {
        c = fmaf(ALPHA, c, h3[((size_t)b * SNN_T + t) * SNN_O + o]);
        p = fmaf(BETA, p, c);
        out[((size_t)b * (SNN_T + 1) + t + 1) * SNN_O + o] = p;
    }
}

// ---------------------------------------------------------------------------
extern "C" void kernel_launch(void* const* d_in, const int* in_sizes, int n_in,
                              void* d_out, int out_size, void* d_ws, size_t ws_size,
                              hipStream_t stream)
{
    const float* X    = (const float*)d_in[0];  // [B,T,F]
    const float* W0   = (const float*)d_in[1];  // [F,H]
    const float* W1   = (const float*)d_in[2];  // [H,H]
    const float* R0   = (const float*)d_in[3];  // [H,H]
    const float* R1   = (const float*)d_in[4];  // [H,H]
    const float* Wout = (const float*)d_in[5];  // [H,O]

    const size_t BT_H = (size_t)SNN_B * SNN_T * SNN_H;  // 26,214,400
    float* out = (float*)d_out;                          // [B,T+1,O]
    float* s1  = out + (size_t)SNN_B * (SNN_T + 1) * SNN_O;
    float* s2  = s1 + BT_H;
    float* v1  = s2 + BT_H;
    float* v2  = v1 + BT_H;

    float* ws   = (float*)d_ws;
    float* hbuf = ws;                       // [B*T*H] (h1, then reused for h2)
    float* h3   = hbuf + BT_H;              // [B*T*O]

    const int M = SNN_B * SNN_T;  // 25600

    // h1 = X @ W0
    gemm_f32<<<dim3(SNN_H / 128, M / 128), 256, 0, stream>>>(X, W0, hbuf, M, SNN_H, SNN_F);

    // layer-1 fused scan (100 steps in one launch)
    lif_scan<<<SNN_B, 1024, 0, stream>>>(hbuf, R0, s1, v1);

    // h2 = s1 @ W1 (reuse hbuf)
    gemm_f32<<<dim3(SNN_H / 128, M / 128), 256, 0, stream>>>(s1, W1, hbuf, M, SNN_H, SNN_H);

    // layer-2 fused scan
    lif_scan<<<SNN_B, 1024, 0, stream>>>(hbuf, R1, s2, v2);

    // readout
    readout_gemm<<<(M * SNN_O) / 256, 256, 0, stream>>>(s2, Wout, h3);
    readout_scan<<<(SNN_B * SNN_O) / 256, 256, 0, stream>>>(h3, out);
}